// Round 6
// baseline (318.587 us; speedup 1.0000x reference)
//
#include <hip/hip_runtime.h>

// NW=32 wavelets, N=M=1024.
#define NPOINTS 1048576ULL
#define NWV 32

typedef _Float16 h8 __attribute__((ext_vector_type(8)));
typedef _Float16 h4 __attribute__((ext_vector_type(4)));
typedef _Float16 h2 __attribute__((ext_vector_type(2)));
typedef float f32x4 __attribute__((ext_vector_type(4)));

// Scaling plan: rowfft applies NO ifft scale (T rms ~45, f16-safe).
// colfft output conv' = 2^20 * conv_true; mod' = sqrt(xx+yy+1e-8*2^40).
// Final reduce multiplies by 2^-20 (einsum 1/(N*M)) * 2^-40 (mod'^2) = 2^-60.

__device__ __forceinline__ float2 cmul(float2 a, float2 b) {
    return make_float2(a.x * b.x - a.y * b.y, a.x * b.y + a.y * b.x);
}
__device__ __forceinline__ float2 csq(float2 a) {
    return make_float2(a.x * a.x - a.y * a.y, 2.f * a.x * a.y);
}
__device__ __forceinline__ void bf(float2& a, float2& b, float2 w) {
    float sx = a.x + b.x, sy = a.y + b.y;
    float dx = a.x - b.x, dy = a.y - b.y;
    a = make_float2(sx, sy);
    b = make_float2(dx * w.x - dy * w.y, dx * w.y + dy * w.x);
}

// 4 DIF radix-2 stages on 16 regs (steps 8,4,2,1). Twiddle for stage s,
// butterfly c is base^(2^s) * W16^c — W16^c are literals (trivial cases
// fold), base powers by complex squaring. No LDS twiddle table.
__device__ __forceinline__ void phase4(float2* X, float2 b0) {
    const float2 C[8] = {
        { 1.f, 0.f },
        { 0.923879532511286756f, 0.382683432365089772f },
        { 0.707106781186547573f, 0.707106781186547462f },
        { 0.382683432365089837f, 0.923879532511286756f },
        { 0.f, 1.f },
        { -0.382683432365089726f, 0.923879532511286756f },
        { -0.707106781186547462f, 0.707106781186547573f },
        { -0.923879532511286756f, 0.382683432365089894f }};
    #pragma unroll
    for (int c = 0; c < 8; ++c) {
        float2 tw = cmul(b0, C[c]);
        bf(X[c], X[c + 8], tw);
    }
    float2 b1 = csq(b0);
    #pragma unroll
    for (int c = 0; c < 4; ++c) {
        float2 tw = cmul(b1, C[2 * c]);
        bf(X[c], X[c + 4], tw);
        bf(X[8 + c], X[12 + c], tw);
    }
    float2 b2 = csq(b1);
    #pragma unroll
    for (int c = 0; c < 2; ++c) {
        float2 tw = cmul(b2, C[4 * c]);
        #pragma unroll
        for (int g = 0; g < 16; g += 4) bf(X[g + c], X[g + c + 2], tw);
    }
    float2 b3 = csq(b2);
    #pragma unroll
    for (int g = 0; g < 16; g += 2) bf(X[g], X[g + 1], b3);
}

// One 1024-pt inverse DIF FFT per 64-lane wave. ex = wave-PRIVATE 1028-entry
// h2 plane (intra-wave exchange only -> no barrier; validated rounds 3-5).
// In: X[k] = elem l+64k. Out: bit-reversed-order slots i = 64*(l>>2)+(l&3)+4j
// (consistent spatial permutation, Gram-safe).
__device__ __forceinline__ void wave_fft(float2* X, int l, h2* __restrict__ ex) {
    float sn, cs;
    sincosf(0.0061359231515425649f * (float)l, &sn, &cs);   // 2*pi*l/1024
    phase4(X, make_float2(cs, sn));                          // half 512..64
    #pragma unroll
    for (int k = 0; k < 16; ++k) {          // XOR-swizzled h2 exchange
        int ph = 64 * k + (l ^ (k << 2));
        ex[ph] = h2{(_Float16)X[k].x, (_Float16)X[k].y};
    }
    const int b = l >> 2, q = l & 3;
    #pragma unroll
    for (int j = 0; j < 16; ++j) {
        int ph = 64 * b + (((q + 4 * j) ^ (b << 2)) & 63);
        h2 v = ex[ph];
        X[j] = make_float2((float)v.x, (float)v.y);
    }
    const float2 W64[4] = {
        { 1.f, 0.f },
        { 0.995184726672196929f, 0.0980171403295606036f },
        { 0.980785280403230449f, 0.195090322016128268f },
        { 0.956940335732208882f, 0.290284677254462333f }};
    phase4(X, W64[q]);                                       // half 32..4
    #pragma unroll
    for (int j = 0; j < 16; ++j) {          // half=2: lane^2, tw 1 / +i
        float ox = __shfl_xor(X[j].x, 2);
        float oy = __shfl_xor(X[j].y, 2);
        if ((l & 2) == 0) { X[j].x += ox; X[j].y += oy; }
        else {
            float dx = ox - X[j].x, dy = oy - X[j].y;
            X[j] = (l & 1) ? make_float2(-dy, dx) : make_float2(dx, dy);
        }
    }
    #pragma unroll
    for (int j = 0; j < 16; ++j) {          // half=1: lane^1, tw 1
        float ox = __shfl_xor(X[j].x, 1);
        float oy = __shfl_xor(X[j].y, 1);
        if ((l & 1) == 0) { X[j].x += ox; X[j].y += oy; }
        else { X[j].x = ox - X[j].x; X[j].y = oy - X[j].y; }
    }
}

// ---------------------------------------------------------------------------
// Pass A: 4 waves/block = 4 rows of one wavelet. Pointwise complex multiply
// (unscaled), wave FFT, restage, block transpose, write T[c][n] f16.
// 256-thr blocks: fine-grained occupancy (VGPR 64->8, 72->7 waves/SIMD...).
// ---------------------------------------------------------------------------
__global__ __launch_bounds__(256, 4) void k_rowfft(
    const float2* __restrict__ xhat, const float* __restrict__ pre,
    const float* __restrict__ pim, _Float16* __restrict__ T, int wbase)
{
    __shared__ h2 ex[4 * 1028];       // 4 per-row planes, stride 1028
    const int t  = threadIdx.x;
    const int wv = t >> 6, l = t & 63;
    const int n  = blockIdx.x * 4 + wv;
    const int wl = blockIdx.y, w = wbase + wl;
    h2* exw = ex + wv * 1028;

    const float2* xr  = xhat + (size_t)n * 1024;
    const float*  prr = pre + (size_t)w * NPOINTS + (size_t)n * 1024;
    const float*  pir = pim + (size_t)w * NPOINTS + (size_t)n * 1024;
    float2 X[16];
    #pragma unroll
    for (int k = 0; k < 16; ++k) {
        float2 x = xr[l + 64 * k];
        float  a = prr[l + 64 * k], bb = pir[l + 64 * k];
        X[k] = make_float2(x.x * a - x.y * bb, x.y * a + x.x * bb);
    }
    wave_fft(X, l, exw);

    // Restage outputs (slot i = 64b+q+4j) into this row's plane.
    const int b = l >> 2, q = l & 3;
    #pragma unroll
    for (int j = 0; j < 16; ++j) {
        int ph = 64 * b + (((q + 4 * j) ^ (b << 2)) & 63);
        exw[ph] = h2{(_Float16)X[j].x, (_Float16)X[j].y};
    }
    __syncthreads();
    // Emit T[c][n0..n0+3]: lane pair (even,odd) covers rows (0,1) and (2,3).
    _Float16* Tw = T + (size_t)wl * NPOINTS * 2;
    const int n0 = blockIdx.x * 4;
    const int u = t >> 1, pr = (t & 1) << 1;
    #pragma unroll
    for (int v = 0; v < 8; ++v) {
        int c  = v * 128 + u;
        int cb = c >> 6, low = c & 63;
        int ph = cb * 64 + ((low ^ (cb << 2)) & 63);
        h2 v0 = ex[pr * 1028 + ph];
        h2 v1 = ex[(pr + 1) * 1028 + ph];
        h4 val = {v0.x, v0.y, v1.x, v1.y};
        *(h4*)&Tw[((size_t)c * 1024 + (size_t)(n0 + pr)) * 2] = val;
    }
}

// ---------------------------------------------------------------------------
// Pass B: 4 waves/block = 4 columns. Coalesced h2 column reads, wave FFT,
// mod' stored f16. ZERO barriers.
// ---------------------------------------------------------------------------
__global__ __launch_bounds__(256, 4) void k_colfft(
    const _Float16* __restrict__ T, _Float16* __restrict__ modb, int wbase)
{
    __shared__ h2 ex[4 * 1028];
    const int t  = threadIdx.x;
    const int wv = t >> 6, l = t & 63;
    const int c  = blockIdx.x * 4 + wv;
    const int wl = blockIdx.y, w = wbase + wl;
    h2* exw = ex + wv * 1028;

    const _Float16* Tc = T + ((size_t)wl * NPOINTS + (size_t)c * 1024) * 2;
    float2 X[16];
    #pragma unroll
    for (int k = 0; k < 16; ++k) {
        h2 v = *(const h2*)&Tc[2 * (64 * k + l)];
        X[k] = make_float2((float)v.x, (float)v.y);
    }
    wave_fft(X, l, exw);

    _Float16* mo = modb + (size_t)w * NPOINTS + (size_t)c * 1024;
    const float epsp = 1.09951162778e4f;   // 1e-8 * 2^40
    #pragma unroll
    for (int qq = 0; qq < 8; ++qq) {
        float m0 = sqrtf(X[2*qq].x * X[2*qq].x + X[2*qq].y * X[2*qq].y + epsp);
        float m1 = sqrtf(X[2*qq+1].x * X[2*qq+1].x + X[2*qq+1].y * X[2*qq+1].y + epsp);
        *(h2*)&mo[2 * (qq * 64 + l)] = h2{(_Float16)m0, (_Float16)m1};
    }
}

// ---------------------------------------------------------------------------
// Pass C: Gram partials via MFMA. Block = 2048 points; c00/c01/c11 quadrants,
// 2048 partial rows (c10 = c01^T never read).
// ---------------------------------------------------------------------------
__global__ __launch_bounds__(256) void k_gram(
    const _Float16* __restrict__ modb, float* __restrict__ part)
{
    __shared__ _Float16 tile[32][520];
    const int t = threadIdx.x;
    const int l = t & 63, wv = t >> 6;
    f32x4 c00 = {0.f,0.f,0.f,0.f}, c01 = {0.f,0.f,0.f,0.f}, c11 = {0.f,0.f,0.f,0.f};
    const size_t pbase = (size_t)blockIdx.x * 2048;

    for (int tt = 0; tt < 4; ++tt) {
        __syncthreads();
        size_t p0 = pbase + (size_t)tt * 512;
        #pragma unroll
        for (int i = 0; i < 8; ++i) {
            int w = i * 4 + wv;
            *(h8*)&tile[w][(size_t)(l * 8)] =
                *(const h8*)&modb[((size_t)w << 20) + p0 + (size_t)(l * 8)];
        }
        __syncthreads();
        #pragma unroll
        for (int s = 0; s < 4; ++s) {
            int k0 = (s * 4 + wv) * 32 + ((l >> 4) * 8);
            h8 a0 = *(const h8*)&tile[l & 15][k0];
            h8 a1 = *(const h8*)&tile[16 + (l & 15)][k0];
            c00 = __builtin_amdgcn_mfma_f32_16x16x32_f16(a0, a0, c00, 0, 0, 0);
            c01 = __builtin_amdgcn_mfma_f32_16x16x32_f16(a0, a1, c01, 0, 0, 0);
            c11 = __builtin_amdgcn_mfma_f32_16x16x32_f16(a1, a1, c11, 0, 0, 0);
        }
    }
    const int row = (blockIdx.x << 2) | wv;     // 2048 partial rows
    float* pr = part + ((size_t)row << 10);
    #pragma unroll
    for (int r = 0; r < 4; ++r) {
        int i = (l >> 4) * 4 + r;    // C/D: col = l&15, row = (l>>4)*4+r
        int j = l & 15;
        pr[i * 32 + j]             = c00[r];
        pr[i * 32 + 16 + j]        = c01[r];
        pr[(16 + i) * 32 + 16 + j] = c11[r];
    }
}

// ---------------------------------------------------------------------------
// Pass D: parallel reduce of part[2048][1024]. 64 blocks x 16 slots;
// 16 chunks of 128 rows per slot, LDS combine. Scale 2^-60.
// ---------------------------------------------------------------------------
__global__ __launch_bounds__(256) void k_reduce(
    const float* __restrict__ part, float* __restrict__ out)
{
    __shared__ float red[16][17];
    const int t = threadIdx.x;
    const int sl    = t & 15;
    const int chunk = t >> 4;
    const int slot  = blockIdx.x * 16 + sl;
    float v = 0.0f;
    const int r0 = chunk * 128;
    for (int i = 0; i < 128; ++i)
        v += part[((size_t)(r0 + i) << 10) + slot];
    red[chunk][sl] = v;
    __syncthreads();
    if (t < 16) {
        float s = 0.0f;
        #pragma unroll
        for (int cch = 0; cch < 16; ++cch) s += red[cch][t];
        int sq = blockIdx.x * 16 + t;
        int i = sq >> 5, j = sq & 31;
        if (j >= i) {
            int q = 32 * i - (i * (i - 1)) / 2 + (j - i);
            if (q < 527) out[q] = s * 8.6736173798840355e-19f;   // 2^-60
        }
    }
}

// ---------------------------------------------------------------------------
extern "C" void kernel_launch(void* const* d_in, const int* in_sizes, int n_in,
                              void* d_out, int out_size, void* d_ws, size_t ws_size,
                              hipStream_t stream) {
    (void)in_sizes; (void)n_in; (void)out_size;
    const float2* xhat = (const float2*)d_in[0];
    const float*  pre  = (const float*)d_in[1];
    const float*  pim  = (const float*)d_in[2];
    float* out = (float*)d_out;

    char* ws = (char*)d_ws;
    _Float16*  modb = (_Float16*)ws;                                // 64 MB
    float*     part = (float*)(ws + NWV * NPOINTS * 2ULL);          // 8 MB
    size_t     Toff = NWV * NPOINTS * 2ULL + 2048ULL * 1024ULL * 4ULL;
    _Float16*  T    = (_Float16*)(ws + Toff);

    // T (f16) batched over wavelets; WB=8 -> 32 MB, L3-resident.
    int WB = 1;
    const int cands[4] = {8, 4, 2, 1};
    for (int c = 0; c < 4; ++c)
        if (Toff + (size_t)cands[c] * NPOINTS * 4ULL <= ws_size) { WB = cands[c]; break; }

    for (int wb = 0; wb < NWV; wb += WB) {
        hipLaunchKernelGGL(k_rowfft, dim3(256, WB), dim3(256), 0, stream,
                           xhat, pre, pim, T, wb);
        hipLaunchKernelGGL(k_colfft, dim3(256, WB), dim3(256), 0, stream,
                           (const _Float16*)T, modb, wb);
    }
    hipLaunchKernelGGL(k_gram, dim3(512), dim3(256), 0, stream,
                       (const _Float16*)modb, part);
    hipLaunchKernelGGL(k_reduce, dim3(64), dim3(256), 0, stream,
                       (const float*)part, out);
}

// Round 7
// 278.565 us; speedup vs baseline: 1.1437x; 1.1437x over previous
//
#include <hip/hip_runtime.h>

// NW=32 wavelets, N=M=1024.
#define NPOINTS 1048576ULL
#define NWV 32
#define ZSTR 40   // h16 stride of [k1][n1]-style 32x32 planes (b128-aligned, low conflict)

typedef _Float16 h8 __attribute__((ext_vector_type(8)));
typedef _Float16 h2 __attribute__((ext_vector_type(2)));
typedef short    s8v __attribute__((ext_vector_type(8)));
typedef float    f32x4 __attribute__((ext_vector_type(4)));

// Scaling plan (same as rounds 3-6): no 1/(N*M) in the FFTs; conv' = 2^20*conv.
// mod' = sqrt(|conv'|^2 + 1e-8*2^40); final scale 2^-60 in k_reduce.

__device__ __forceinline__ f32x4 MF(h8 a, h8 b, f32x4 c) {
    return __builtin_amdgcn_mfma_f32_16x16x32_f16(a, b, c, 0, 0, 0);
}
__device__ __forceinline__ h8 hneg(h8 x) {
    s8v s = *(s8v*)&x;
    s = s ^ (short)0x8000;
    return *(h8*)&s;
}

// Build per-block tables: TW[a*32+b] = W1024^(a*b) (f32), F[a][b] = W32^(a*b) (f16
// planes, stride ZSTR). Both symmetric in (a,b).
__device__ __forceinline__ void build_tables(int t, float2* TW, _Float16* Fr, _Float16* Fi) {
    for (int i = t; i < 1024; i += 256) {
        int a = i >> 5, b = i & 31;
        float sn, cs;
        sincosf(0.0061359231515425649f * (float)(a * b), &sn, &cs);      // 2pi/1024
        TW[i] = make_float2(cs, sn);
        float sn2, cs2;
        sincosf(0.19634954084936207f * (float)((a * b) & 31), &sn2, &cs2); // 2pi/32
        Fr[a * ZSTR + b] = (_Float16)cs2;
        Fi[a * ZSTR + b] = (_Float16)sn2;
    }
}

struct EOut { f32x4 r00, r01, r10, r11, i00, i01, i10, i11; };

// One 1024-pt inverse FFT per wave via four-step (32x32):
//  step1 D = X^T * F   (A-frags ar/ai: row n2 = 16*QI + c16, k = n1 = 8g+j)
//  twiddle Z(n2,k1) = D(n2,k1) * W1024^(n2*k1), staged f16 in wave-private planes
//  step3 E = Zmat * F  -> E[k1][k2], output index k = k1 + 32*k2 (natural order).
// Quadrant regs: e.g. r01 is QI=0 (rows 0-15), QJ=1 (cols 16-31).
__device__ __forceinline__ EOut fft_core(
    h8 ar0, h8 ai0, h8 ar1, h8 ai1,
    h8 fr0, h8 fr1, h8 fi0, h8 fi1, h8 mfi0, h8 mfi1,
    const float2* __restrict__ TW,
    _Float16* __restrict__ Zr, _Float16* __restrict__ Zi,
    int g, int c16)
{
    const f32x4 z = {0.f, 0.f, 0.f, 0.f};
    f32x4 dr00=z, dr01=z, dr10=z, dr11=z, di00=z, di01=z, di10=z, di11=z;
    dr00 = MF(ar0, fr0, dr00); dr00 = MF(ai0, mfi0, dr00);
    di00 = MF(ar0, fi0, di00); di00 = MF(ai0, fr0,  di00);
    dr01 = MF(ar0, fr1, dr01); dr01 = MF(ai0, mfi1, dr01);
    di01 = MF(ar0, fi1, di01); di01 = MF(ai0, fr1,  di01);
    dr10 = MF(ar1, fr0, dr10); dr10 = MF(ai1, mfi0, dr10);
    di10 = MF(ar1, fi0, di10); di10 = MF(ai1, fr0,  di10);
    dr11 = MF(ar1, fr1, dr11); dr11 = MF(ai1, mfi1, dr11);
    di11 = MF(ar1, fi1, di11); di11 = MF(ai1, fr1,  di11);

    // Twiddle + stage Z into wave-private planes [k1][n2] (no barrier needed:
    // intra-wave LDS ordering, pattern validated rounds 3-6).
#define TWZ(DR, DI, QI, QJ)                                                    \
    {                                                                          \
        const int k1 = 16 * (QJ) + c16;                                        \
        _Pragma("unroll")                                                      \
        for (int rp = 0; rp < 2; ++rp) {                                       \
            const int n2 = 16 * (QI) + 4 * g + 2 * rp;                         \
            float2 tA = TW[n2 * 32 + k1];                                      \
            float2 tB = TW[(n2 + 1) * 32 + k1];                                \
            float yr0 = DR[2*rp],   yi0 = DI[2*rp];                            \
            float yr1 = DR[2*rp+1], yi1 = DI[2*rp+1];                          \
            h2 zr2 = { (_Float16)(yr0*tA.x - yi0*tA.y),                        \
                       (_Float16)(yr1*tB.x - yi1*tB.y) };                      \
            h2 zi2 = { (_Float16)(yi0*tA.x + yr0*tA.y),                        \
                       (_Float16)(yi1*tB.x + yr1*tB.y) };                      \
            *(h2*)&Zr[k1 * ZSTR + n2] = zr2;                                   \
            *(h2*)&Zi[k1 * ZSTR + n2] = zi2;                                   \
        }                                                                      \
    }
    TWZ(dr00, di00, 0, 0) TWZ(dr01, di01, 0, 1)
    TWZ(dr10, di10, 1, 0) TWZ(dr11, di11, 1, 1)
#undef TWZ

    h8 a3r0 = *(h8*)&Zr[c16 * ZSTR + 8 * g];
    h8 a3i0 = *(h8*)&Zi[c16 * ZSTR + 8 * g];
    h8 a3r1 = *(h8*)&Zr[(16 + c16) * ZSTR + 8 * g];
    h8 a3i1 = *(h8*)&Zi[(16 + c16) * ZSTR + 8 * g];

    EOut e;
    e.r00 = MF(a3r0, fr0, z); e.r00 = MF(a3i0, mfi0, e.r00);
    e.i00 = MF(a3r0, fi0, z); e.i00 = MF(a3i0, fr0,  e.i00);
    e.r01 = MF(a3r0, fr1, z); e.r01 = MF(a3i0, mfi1, e.r01);
    e.i01 = MF(a3r0, fi1, z); e.i01 = MF(a3i0, fr1,  e.i01);
    e.r10 = MF(a3r1, fr0, z); e.r10 = MF(a3i1, mfi0, e.r10);
    e.i10 = MF(a3r1, fi0, z); e.i10 = MF(a3i1, fr0,  e.i10);
    e.r11 = MF(a3r1, fr1, z); e.r11 = MF(a3i1, mfi1, e.r11);
    e.i11 = MF(a3r1, fi1, z); e.i11 = MF(a3i1, fr1,  e.i11);
    return e;
}

// ---------------------------------------------------------------------------
// Pass A: 4 waves/block = 4 rows of one wavelet. Pointwise complex multiply
// loaded DIRECTLY in fragment order from global (coalesced 64B segments),
// MFMA four-step FFT, block LDS transpose, T[k][n0..3] u32 (h2 complex).
// ---------------------------------------------------------------------------
__global__ __launch_bounds__(256, 3) void k_rowfft(
    const float2* __restrict__ xhat, const float* __restrict__ pre,
    const float* __restrict__ pim, unsigned int* __restrict__ T, int wbase)
{
    __shared__ float2   TW[1024];
    __shared__ _Float16 Fr[1280], Fi[1280];
    __shared__ _Float16 ZS[4][2][1280];
    __shared__ unsigned int Ttile[4220];   // [k2]*132 + [k1]*4 + row
    const int t = threadIdx.x, wv = t >> 6, l = t & 63, g = l >> 4, c16 = l & 15;
    const int n = blockIdx.x * 4 + wv;
    const int wl = blockIdx.y, w = wbase + wl;

    build_tables(t, TW, Fr, Fi);
    __syncthreads();

    h8 fr0 = *(h8*)&Fr[c16 * ZSTR + 8 * g];
    h8 fr1 = *(h8*)&Fr[(16 + c16) * ZSTR + 8 * g];
    h8 fi0 = *(h8*)&Fi[c16 * ZSTR + 8 * g];
    h8 fi1 = *(h8*)&Fi[(16 + c16) * ZSTR + 8 * g];
    h8 mfi0 = hneg(fi0), mfi1 = hneg(fi1);

    const float*  prr = pre + (size_t)w * NPOINTS + (size_t)n * 1024;
    const float*  pir = pim + (size_t)w * NPOINTS + (size_t)n * 1024;
    const float2* xr  = xhat + (size_t)n * 1024;
    h8 ar0, ai0, ar1, ai1;
    #pragma unroll
    for (int j = 0; j < 8; ++j) {
        int m0 = 32 * (8 * g + j) + c16;       // QI=0
        float a = prr[m0], b = pir[m0];
        float2 x = xr[m0];
        ar0[j] = (_Float16)(x.x * a - x.y * b);
        ai0[j] = (_Float16)(x.y * a + x.x * b);
        int m1 = m0 + 16;                      // QI=1
        float a1 = prr[m1], b1 = pir[m1];
        float2 x1 = xr[m1];
        ar1[j] = (_Float16)(x1.x * a1 - x1.y * b1);
        ai1[j] = (_Float16)(x1.y * a1 + x1.x * b1);
    }

    EOut e = fft_core(ar0, ai0, ar1, ai1, fr0, fr1, fi0, fi1, mfi0, mfi1,
                      TW, &ZS[wv][0][0], &ZS[wv][1][0], g, c16);

    // Emit to block tile: element (k1 = 16QI+4g+r, k2 = 16QJ+c16).
#define EMIT(ER, EI, QI, QJ)                                                   \
    _Pragma("unroll")                                                          \
    for (int r = 0; r < 4; ++r) {                                              \
        int k1 = 16 * (QI) + 4 * g + r, k2 = 16 * (QJ) + c16;                  \
        h2 p = { (_Float16)ER[r], (_Float16)EI[r] };                           \
        Ttile[k2 * 132 + k1 * 4 + wv] = *(unsigned int*)&p;                    \
    }
    EMIT(e.r00, e.i00, 0, 0) EMIT(e.r01, e.i01, 0, 1)
    EMIT(e.r10, e.i10, 1, 0) EMIT(e.r11, e.i11, 1, 1)
#undef EMIT
    __syncthreads();

    unsigned int* Tw = T + (size_t)wl * NPOINTS;
    const int n0 = blockIdx.x * 4;
    #pragma unroll
    for (int jj = 0; jj < 4; ++jj) {
        int k = t + 256 * jj;
        uint4 v = *(uint4*)&Ttile[(k >> 5) * 132 + (k & 31) * 4];
        *(uint4*)&Tw[(size_t)k * 1024 + n0] = v;
    }
}

// ---------------------------------------------------------------------------
// Pass B: 4 waves/block = 4 columns (T rows). Coalesced u32 loads in fragment
// order (data already f16 — no cvt), MFMA four-step FFT, modulus, coalesced
// packed-h2 mod stores via a wave-private f32 tile.
// ---------------------------------------------------------------------------
__global__ __launch_bounds__(256, 3) void k_colfft(
    const unsigned int* __restrict__ T, _Float16* __restrict__ modb, int wbase)
{
    __shared__ float2   TW[1024];
    __shared__ _Float16 Fr[1280], Fi[1280];
    __shared__ _Float16 ZS[4][2][1280];
    __shared__ float    Mt[4][1216];       // per wave: [kap2]*38 + [kap1]
    const int t = threadIdx.x, wv = t >> 6, l = t & 63, g = l >> 4, c16 = l & 15;
    const int k = blockIdx.x * 4 + wv;
    const int wl = blockIdx.y, w = wbase + wl;

    build_tables(t, TW, Fr, Fi);
    __syncthreads();

    h8 fr0 = *(h8*)&Fr[c16 * ZSTR + 8 * g];
    h8 fr1 = *(h8*)&Fr[(16 + c16) * ZSTR + 8 * g];
    h8 fi0 = *(h8*)&Fi[c16 * ZSTR + 8 * g];
    h8 fi1 = *(h8*)&Fi[(16 + c16) * ZSTR + 8 * g];
    h8 mfi0 = hneg(fi0), mfi1 = hneg(fi1);

    const unsigned int* Tc = T + (size_t)wl * NPOINTS + (size_t)k * 1024;
    h8 ar0, ai0, ar1, ai1;
    #pragma unroll
    for (int j = 0; j < 8; ++j) {
        unsigned int v0 = Tc[32 * (8 * g + j) + c16];
        unsigned int v1 = Tc[32 * (8 * g + j) + 16 + c16];
        h2 p0 = *(h2*)&v0, p1 = *(h2*)&v1;
        ar0[j] = p0.x; ai0[j] = p0.y;
        ar1[j] = p1.x; ai1[j] = p1.y;
    }

    EOut e = fft_core(ar0, ai0, ar1, ai1, fr0, fr1, fi0, fi1, mfi0, mfi1,
                      TW, &ZS[wv][0][0], &ZS[wv][1][0], g, c16);

    float* mt = Mt[wv];
    const float epsp = 1.09951162778e4f;   // 1e-8 * 2^40
#define EMITM(ER, EI, QI, QJ)                                                  \
    _Pragma("unroll")                                                          \
    for (int r = 0; r < 4; ++r) {                                              \
        int K1 = 16 * (QI) + 4 * g + r, K2 = 16 * (QJ) + c16;                  \
        float xr_ = ER[r], xi_ = EI[r];                                        \
        mt[K2 * 38 + K1] = sqrtf(xr_ * xr_ + xi_ * xi_ + epsp);                \
    }
    EMITM(e.r00, e.i00, 0, 0) EMITM(e.r01, e.i01, 0, 1)
    EMITM(e.r10, e.i10, 1, 0) EMITM(e.r11, e.i11, 1, 1)
#undef EMITM

    // Wave-local readout (no barrier): p = 2l + 128*ii, natural order.
    unsigned int* mo = (unsigned int*)(modb + (size_t)w * NPOINTS + (size_t)k * 1024);
    #pragma unroll
    for (int ii = 0; ii < 8; ++ii) {
        int p = 2 * l + 128 * ii;
        int K1 = p & 31, K2 = p >> 5;
        h2 hm = { (_Float16)mt[K2 * 38 + K1], (_Float16)mt[K2 * 38 + K1 + 1] };
        mo[l + 64 * ii] = *(unsigned int*)&hm;
    }
}

// ---------------------------------------------------------------------------
// Pass C: Gram partials via MFMA (unchanged, validated). 2048 partial rows.
// ---------------------------------------------------------------------------
__global__ __launch_bounds__(256) void k_gram(
    const _Float16* __restrict__ modb, float* __restrict__ part)
{
    __shared__ _Float16 tile[32][520];
    const int t = threadIdx.x;
    const int l = t & 63, wv = t >> 6;
    f32x4 c00 = {0.f,0.f,0.f,0.f}, c01 = {0.f,0.f,0.f,0.f}, c11 = {0.f,0.f,0.f,0.f};
    const size_t pbase = (size_t)blockIdx.x * 2048;

    for (int tt = 0; tt < 4; ++tt) {
        __syncthreads();
        size_t p0 = pbase + (size_t)tt * 512;
        #pragma unroll
        for (int i = 0; i < 8; ++i) {
            int w = i * 4 + wv;
            *(h8*)&tile[w][(size_t)(l * 8)] =
                *(const h8*)&modb[((size_t)w << 20) + p0 + (size_t)(l * 8)];
        }
        __syncthreads();
        #pragma unroll
        for (int s = 0; s < 4; ++s) {
            int k0 = (s * 4 + wv) * 32 + ((l >> 4) * 8);
            h8 a0 = *(const h8*)&tile[l & 15][k0];
            h8 a1 = *(const h8*)&tile[16 + (l & 15)][k0];
            c00 = __builtin_amdgcn_mfma_f32_16x16x32_f16(a0, a0, c00, 0, 0, 0);
            c01 = __builtin_amdgcn_mfma_f32_16x16x32_f16(a0, a1, c01, 0, 0, 0);
            c11 = __builtin_amdgcn_mfma_f32_16x16x32_f16(a1, a1, c11, 0, 0, 0);
        }
    }
    const int row = (blockIdx.x << 2) | wv;
    float* pr = part + ((size_t)row << 10);
    #pragma unroll
    for (int r = 0; r < 4; ++r) {
        int i = (l >> 4) * 4 + r;
        int j = l & 15;
        pr[i * 32 + j]             = c00[r];
        pr[i * 32 + 16 + j]        = c01[r];
        pr[(16 + i) * 32 + 16 + j] = c11[r];
    }
}

// ---------------------------------------------------------------------------
// Pass D: parallel reduce of part[2048][1024]; triangle map; scale 2^-60.
// ---------------------------------------------------------------------------
__global__ __launch_bounds__(256) void k_reduce(
    const float* __restrict__ part, float* __restrict__ out)
{
    __shared__ float red[16][17];
    const int t = threadIdx.x;
    const int sl    = t & 15;
    const int chunk = t >> 4;
    const int slot  = blockIdx.x * 16 + sl;
    float v = 0.0f;
    const int r0 = chunk * 128;
    for (int i = 0; i < 128; ++i)
        v += part[((size_t)(r0 + i) << 10) + slot];
    red[chunk][sl] = v;
    __syncthreads();
    if (t < 16) {
        float s = 0.0f;
        #pragma unroll
        for (int cch = 0; cch < 16; ++cch) s += red[cch][t];
        int sq = blockIdx.x * 16 + t;
        int i = sq >> 5, j = sq & 31;
        if (j >= i) {
            int q = 32 * i - (i * (i - 1)) / 2 + (j - i);
            if (q < 527) out[q] = s * 8.6736173798840355e-19f;   // 2^-60
        }
    }
}

// ---------------------------------------------------------------------------
extern "C" void kernel_launch(void* const* d_in, const int* in_sizes, int n_in,
                              void* d_out, int out_size, void* d_ws, size_t ws_size,
                              hipStream_t stream) {
    (void)in_sizes; (void)n_in; (void)out_size;
    const float2* xhat = (const float2*)d_in[0];
    const float*  pre  = (const float*)d_in[1];
    const float*  pim  = (const float*)d_in[2];
    float* out = (float*)d_out;

    char* ws = (char*)d_ws;
    _Float16*     modb = (_Float16*)ws;                              // 64 MB
    float*        part = (float*)(ws + NWV * NPOINTS * 2ULL);        // 8 MB
    size_t        Toff = NWV * NPOINTS * 2ULL + 2048ULL * 1024ULL * 4ULL;
    unsigned int* T    = (unsigned int*)(ws + Toff);                 // WB*4 MB

    int WB = 1;
    const int cands[4] = {8, 4, 2, 1};
    for (int c = 0; c < 4; ++c)
        if (Toff + (size_t)cands[c] * NPOINTS * 4ULL <= ws_size) { WB = cands[c]; break; }

    for (int wb = 0; wb < NWV; wb += WB) {
        hipLaunchKernelGGL(k_rowfft, dim3(256, WB), dim3(256), 0, stream,
                           xhat, pre, pim, T, wb);
        hipLaunchKernelGGL(k_colfft, dim3(256, WB), dim3(256), 0, stream,
                           (const unsigned int*)T, modb, wb);
    }
    hipLaunchKernelGGL(k_gram, dim3(512), dim3(256), 0, stream,
                       (const _Float16*)modb, part);
    hipLaunchKernelGGL(k_reduce, dim3(64), dim3(256), 0, stream,
                       (const float*)part, out);
}

// Round 8
// 275.730 us; speedup vs baseline: 1.1554x; 1.0103x over previous
//
#include <hip/hip_runtime.h>

// NW=32 wavelets, N=M=1024.
#define NPOINTS 1048576ULL
#define NWV 32
#define ZSTR 40   // h16 stride of [k1][n2] Z planes (16B-aligned rows)
#define PSTR 34   // u32 stride of stage plane [n2][n1] (2-way-free banks)

typedef _Float16 h8 __attribute__((ext_vector_type(8)));
typedef _Float16 h2 __attribute__((ext_vector_type(2)));
typedef short    s8v __attribute__((ext_vector_type(8)));
typedef float    f32x4 __attribute__((ext_vector_type(4)));

// Scaling plan (rounds 3-7): no 1/(N*M) in the FFTs; conv' = 2^20*conv.
// mod' = sqrt(|conv'|^2 + 1e-8*2^40); final scale 2^-60 in k_reduce.

__device__ __forceinline__ f32x4 MF(h8 a, h8 b, f32x4 c) {
    return __builtin_amdgcn_mfma_f32_16x16x32_f16(a, b, c, 0, 0, 0);
}
__device__ __forceinline__ h8 hneg(h8 x) {
    s8v s = *(s8v*)&x;
    s = s ^ (short)0x8000;
    return *(h8*)&s;
}

// Per-block tables: TW[a*32+b] = W1024^(a*b) (f32), F[a][b] = W32^(a*b) (f16).
__device__ __forceinline__ void build_tables(int t, float2* TW, _Float16* Fr, _Float16* Fi) {
    for (int i = t; i < 1024; i += 256) {
        int a = i >> 5, b = i & 31;
        float sn, cs;
        sincosf(0.0061359231515425649f * (float)(a * b), &sn, &cs);        // 2pi/1024
        TW[i] = make_float2(cs, sn);
        float sn2, cs2;
        sincosf(0.19634954084936207f * (float)((a * b) & 31), &sn2, &cs2); // 2pi/32
        Fr[a * ZSTR + b] = (_Float16)cs2;
        Fi[a * ZSTR + b] = (_Float16)sn2;
    }
}

// Unpack staged u32 (h2{re,im}) plane into MFMA A-fragments.
// A[row=n2][k=n1]: lane (g,c16) takes n2 = c16 (+16), n1 = 8g..8g+7.
__device__ __forceinline__ void load_frags(const unsigned int* __restrict__ pl,
    int g, int c16, h8& ar0, h8& ai0, h8& ar1, h8& ai1)
{
    #pragma unroll
    for (int j = 0; j < 8; ++j) {
        unsigned int v0 = pl[PSTR * c16 + 8 * g + j];
        unsigned int v1 = pl[PSTR * (16 + c16) + 8 * g + j];
        h2 p0 = *(h2*)&v0, p1 = *(h2*)&v1;
        ar0[j] = p0.x; ai0[j] = p0.y;
        ar1[j] = p1.x; ai1[j] = p1.y;
    }
}

struct EOut { f32x4 r00, r01, r10, r11, i00, i01, i10, i11; };

// 1024-pt inverse FFT per wave, four-step 32x32 (validated round 7):
//  step1 D = X^T*F, twiddle by W1024^(n2*k1) staged f16 to wave-private Z,
//  step3 E = Z*F -> E[k1][k2], natural output order k = k1 + 32*k2.
__device__ __forceinline__ EOut fft_core(
    h8 ar0, h8 ai0, h8 ar1, h8 ai1,
    h8 fr0, h8 fr1, h8 fi0, h8 fi1, h8 mfi0, h8 mfi1,
    const float2* __restrict__ TW,
    _Float16* __restrict__ Zr, _Float16* __restrict__ Zi,
    int g, int c16)
{
    const f32x4 z = {0.f, 0.f, 0.f, 0.f};
    f32x4 dr00=z, dr01=z, dr10=z, dr11=z, di00=z, di01=z, di10=z, di11=z;
    dr00 = MF(ar0, fr0, dr00); dr00 = MF(ai0, mfi0, dr00);
    di00 = MF(ar0, fi0, di00); di00 = MF(ai0, fr0,  di00);
    dr01 = MF(ar0, fr1, dr01); dr01 = MF(ai0, mfi1, dr01);
    di01 = MF(ar0, fi1, di01); di01 = MF(ai0, fr1,  di01);
    dr10 = MF(ar1, fr0, dr10); dr10 = MF(ai1, mfi0, dr10);
    di10 = MF(ar1, fi0, di10); di10 = MF(ai1, fr0,  di10);
    dr11 = MF(ar1, fr1, dr11); dr11 = MF(ai1, mfi1, dr11);
    di11 = MF(ar1, fi1, di11); di11 = MF(ai1, fr1,  di11);

#define TWZ(DR, DI, QI, QJ)                                                    \
    {                                                                          \
        const int k1 = 16 * (QJ) + c16;                                        \
        _Pragma("unroll")                                                      \
        for (int rp = 0; rp < 2; ++rp) {                                       \
            const int n2 = 16 * (QI) + 4 * g + 2 * rp;                         \
            float2 tA = TW[n2 * 32 + k1];                                      \
            float2 tB = TW[(n2 + 1) * 32 + k1];                                \
            float yr0 = DR[2*rp],   yi0 = DI[2*rp];                            \
            float yr1 = DR[2*rp+1], yi1 = DI[2*rp+1];                          \
            h2 zr2 = { (_Float16)(yr0*tA.x - yi0*tA.y),                        \
                       (_Float16)(yr1*tB.x - yi1*tB.y) };                      \
            h2 zi2 = { (_Float16)(yi0*tA.x + yr0*tA.y),                        \
                       (_Float16)(yi1*tB.x + yr1*tB.y) };                      \
            *(h2*)&Zr[k1 * ZSTR + n2] = zr2;                                   \
            *(h2*)&Zi[k1 * ZSTR + n2] = zi2;                                   \
        }                                                                      \
    }
    TWZ(dr00, di00, 0, 0) TWZ(dr01, di01, 0, 1)
    TWZ(dr10, di10, 1, 0) TWZ(dr11, di11, 1, 1)
#undef TWZ

    h8 a3r0 = *(h8*)&Zr[c16 * ZSTR + 8 * g];
    h8 a3i0 = *(h8*)&Zi[c16 * ZSTR + 8 * g];
    h8 a3r1 = *(h8*)&Zr[(16 + c16) * ZSTR + 8 * g];
    h8 a3i1 = *(h8*)&Zi[(16 + c16) * ZSTR + 8 * g];

    EOut e;
    e.r00 = MF(a3r0, fr0, z); e.r00 = MF(a3i0, mfi0, e.r00);
    e.i00 = MF(a3r0, fi0, z); e.i00 = MF(a3i0, fr0,  e.i00);
    e.r01 = MF(a3r0, fr1, z); e.r01 = MF(a3i0, mfi1, e.r01);
    e.i01 = MF(a3r0, fi1, z); e.i01 = MF(a3i0, fr1,  e.i01);
    e.r10 = MF(a3r1, fr0, z); e.r10 = MF(a3i1, mfi0, e.r10);
    e.i10 = MF(a3r1, fi0, z); e.i10 = MF(a3i1, fr0,  e.i10);
    e.r11 = MF(a3r1, fr1, z); e.r11 = MF(a3i1, mfi1, e.r11);
    e.i11 = MF(a3r1, fi1, z); e.i11 = MF(a3i1, fr1,  e.i11);
    return e;
}

// ---------------------------------------------------------------------------
// Pass A: 4 waves/block = 4 rows of one wavelet. Vectorized dwordx4 loads in
// NATURAL order, pointwise complex multiply, h2-pack staged to per-wave LDS
// plane, fragment unpack, MFMA FFT, block transpose, T[k][n0..3] 16B stores.
// LDS: TW 8K + F 5K + WSP union 20.5K = 33.5K -> 4 blocks/CU.
// ---------------------------------------------------------------------------
__global__ __launch_bounds__(256, 4) void k_rowfft(
    const float* __restrict__ xhat, const float* __restrict__ pre,
    const float* __restrict__ pim, unsigned int* __restrict__ T, int wbase)
{
    __shared__ float2   TW[1024];
    __shared__ _Float16 Fr[1280], Fi[1280];
    __shared__ unsigned int WSP[4][1312];   // per-wave stage/Z union; Ttile union
    const int t = threadIdx.x, wv = t >> 6, l = t & 63, g = l >> 4, c16 = l & 15;
    const int n = blockIdx.x * 4 + wv;
    const int wl = blockIdx.y, w = wbase + wl;

    build_tables(t, TW, Fr, Fi);
    __syncthreads();

    h8 fr0 = *(h8*)&Fr[c16 * ZSTR + 8 * g];
    h8 fr1 = *(h8*)&Fr[(16 + c16) * ZSTR + 8 * g];
    h8 fi0 = *(h8*)&Fi[c16 * ZSTR + 8 * g];
    h8 fi1 = *(h8*)&Fi[(16 + c16) * ZSTR + 8 * g];
    h8 mfi0 = hneg(fi0), mfi1 = hneg(fi1);

    // Stage: m = 256c + 4l + i  ->  n1 = 8c + (l>>3), n2 = 4*(l&7) + i.
    unsigned int* pl = &WSP[wv][0];
    const float4* pr4 = (const float4*)(pre + (size_t)w * NPOINTS + (size_t)n * 1024);
    const float4* pi4 = (const float4*)(pim + (size_t)w * NPOINTS + (size_t)n * 1024);
    const float4* xh4 = (const float4*)(xhat + (size_t)n * 2048);  // 2 complex per float4
    const int n2b = 4 * (l & 7), n1b = l >> 3;
    #pragma unroll
    for (int c = 0; c < 4; ++c) {
        float4 a  = pr4[64 * c + l];
        float4 b  = pi4[64 * c + l];
        float4 x0 = xh4[128 * c + 2 * l];
        float4 x1 = xh4[128 * c + 2 * l + 1];
        float xr[4] = {x0.x, x0.z, x1.x, x1.z};
        float xi[4] = {x0.y, x0.w, x1.y, x1.w};
        float pa[4] = {a.x, a.y, a.z, a.w};
        float pb[4] = {b.x, b.y, b.z, b.w};
        const int n1 = 8 * c + n1b;
        #pragma unroll
        for (int i = 0; i < 4; ++i) {
            float re = xr[i] * pa[i] - xi[i] * pb[i];
            float im = xi[i] * pa[i] + xr[i] * pb[i];
            h2 p = {(_Float16)re, (_Float16)im};
            pl[PSTR * (n2b + i) + n1] = *(unsigned int*)&p;
        }
    }
    h8 ar0, ai0, ar1, ai1;
    load_frags(pl, g, c16, ar0, ai0, ar1, ai1);   // intra-wave: no barrier

    EOut e = fft_core(ar0, ai0, ar1, ai1, fr0, fr1, fi0, fi1, mfi0, mfi1,
                      TW, (_Float16*)&WSP[wv][0], (_Float16*)&WSP[wv][0] + 1280,
                      g, c16);

    __syncthreads();                 // all waves done with private planes
    unsigned int* Ttile = &WSP[0][0];       // [k2]*132 + [k1]*4 + wv
#define EMIT(ER, EI, QI, QJ)                                                   \
    _Pragma("unroll")                                                          \
    for (int r = 0; r < 4; ++r) {                                              \
        int k1 = 16 * (QI) + 4 * g + r, k2 = 16 * (QJ) + c16;                  \
        h2 p = { (_Float16)ER[r], (_Float16)EI[r] };                           \
        Ttile[k2 * 132 + k1 * 4 + wv] = *(unsigned int*)&p;                    \
    }
    EMIT(e.r00, e.i00, 0, 0) EMIT(e.r01, e.i01, 0, 1)
    EMIT(e.r10, e.i10, 1, 0) EMIT(e.r11, e.i11, 1, 1)
#undef EMIT
    __syncthreads();

    unsigned int* Tw = T + (size_t)wl * NPOINTS;
    const int n0 = blockIdx.x * 4;
    #pragma unroll
    for (int jj = 0; jj < 4; ++jj) {
        int k = t + 256 * jj;
        uint4 v = *(uint4*)&Ttile[(k >> 5) * 132 + (k & 31) * 4];
        *(uint4*)&Tw[(size_t)k * 1024 + n0] = v;
    }
}

// ---------------------------------------------------------------------------
// Pass B: 4 waves/block = 4 columns. Vectorized uint4 natural-order loads,
// LDS re-stage, fragment unpack, MFMA FFT, modulus, coalesced h2 stores.
// Barrier-free after table build.
// ---------------------------------------------------------------------------
__global__ __launch_bounds__(256, 4) void k_colfft(
    const unsigned int* __restrict__ T, _Float16* __restrict__ modb, int wbase)
{
    __shared__ float2   TW[1024];
    __shared__ _Float16 Fr[1280], Fi[1280];
    __shared__ unsigned int WSP[4][1312];
    const int t = threadIdx.x, wv = t >> 6, l = t & 63, g = l >> 4, c16 = l & 15;
    const int k = blockIdx.x * 4 + wv;
    const int wl = blockIdx.y, w = wbase + wl;

    build_tables(t, TW, Fr, Fi);
    __syncthreads();

    h8 fr0 = *(h8*)&Fr[c16 * ZSTR + 8 * g];
    h8 fr1 = *(h8*)&Fr[(16 + c16) * ZSTR + 8 * g];
    h8 fi0 = *(h8*)&Fi[c16 * ZSTR + 8 * g];
    h8 fi1 = *(h8*)&Fi[(16 + c16) * ZSTR + 8 * g];
    h8 mfi0 = hneg(fi0), mfi1 = hneg(fi1);

    unsigned int* pl = &WSP[wv][0];
    const uint4* Tc4 = (const uint4*)(T + (size_t)wl * NPOINTS + (size_t)k * 1024);
    const int n2b = 4 * (l & 7), n1b = l >> 3;
    #pragma unroll
    for (int c = 0; c < 4; ++c) {
        uint4 v = Tc4[64 * c + l];
        const int n1 = 8 * c + n1b;
        pl[PSTR * (n2b + 0) + n1] = v.x;
        pl[PSTR * (n2b + 1) + n1] = v.y;
        pl[PSTR * (n2b + 2) + n1] = v.z;
        pl[PSTR * (n2b + 3) + n1] = v.w;
    }
    h8 ar0, ai0, ar1, ai1;
    load_frags(pl, g, c16, ar0, ai0, ar1, ai1);

    EOut e = fft_core(ar0, ai0, ar1, ai1, fr0, fr1, fi0, fi1, mfi0, mfi1,
                      TW, (_Float16*)&WSP[wv][0], (_Float16*)&WSP[wv][0] + 1280,
                      g, c16);

    float* mt = (float*)&WSP[wv][0];       // [k2]*38 + [k1]; own Z is dead
    const float epsp = 1.09951162778e4f;   // 1e-8 * 2^40
#define EMITM(ER, EI, QI, QJ)                                                  \
    _Pragma("unroll")                                                          \
    for (int r = 0; r < 4; ++r) {                                              \
        int K1 = 16 * (QI) + 4 * g + r, K2 = 16 * (QJ) + c16;                  \
        float xr_ = ER[r], xi_ = EI[r];                                        \
        mt[K2 * 38 + K1] = sqrtf(xr_ * xr_ + xi_ * xi_ + epsp);                \
    }
    EMITM(e.r00, e.i00, 0, 0) EMITM(e.r01, e.i01, 0, 1)
    EMITM(e.r10, e.i10, 1, 0) EMITM(e.r11, e.i11, 1, 1)
#undef EMITM

    unsigned int* mo = (unsigned int*)(modb + (size_t)w * NPOINTS + (size_t)k * 1024);
    #pragma unroll
    for (int ii = 0; ii < 8; ++ii) {
        int p = 2 * l + 128 * ii;
        int K1 = p & 31, K2 = p >> 5;
        h2 hm = { (_Float16)mt[K2 * 38 + K1], (_Float16)mt[K2 * 38 + K1 + 1] };
        mo[l + 64 * ii] = *(unsigned int*)&hm;
    }
}

// ---------------------------------------------------------------------------
// Pass C: Gram partials via MFMA (validated). 2048 partial rows.
// ---------------------------------------------------------------------------
__global__ __launch_bounds__(256) void k_gram(
    const _Float16* __restrict__ modb, float* __restrict__ part)
{
    __shared__ _Float16 tile[32][520];
    const int t = threadIdx.x;
    const int l = t & 63, wv = t >> 6;
    f32x4 c00 = {0.f,0.f,0.f,0.f}, c01 = {0.f,0.f,0.f,0.f}, c11 = {0.f,0.f,0.f,0.f};
    const size_t pbase = (size_t)blockIdx.x * 2048;

    for (int tt = 0; tt < 4; ++tt) {
        __syncthreads();
        size_t p0 = pbase + (size_t)tt * 512;
        #pragma unroll
        for (int i = 0; i < 8; ++i) {
            int w = i * 4 + wv;
            *(h8*)&tile[w][(size_t)(l * 8)] =
                *(const h8*)&modb[((size_t)w << 20) + p0 + (size_t)(l * 8)];
        }
        __syncthreads();
        #pragma unroll
        for (int s = 0; s < 4; ++s) {
            int k0 = (s * 4 + wv) * 32 + ((l >> 4) * 8);
            h8 a0 = *(const h8*)&tile[l & 15][k0];
            h8 a1 = *(const h8*)&tile[16 + (l & 15)][k0];
            c00 = __builtin_amdgcn_mfma_f32_16x16x32_f16(a0, a0, c00, 0, 0, 0);
            c01 = __builtin_amdgcn_mfma_f32_16x16x32_f16(a0, a1, c01, 0, 0, 0);
            c11 = __builtin_amdgcn_mfma_f32_16x16x32_f16(a1, a1, c11, 0, 0, 0);
        }
    }
    const int row = (blockIdx.x << 2) | wv;
    float* pr = part + ((size_t)row << 10);
    #pragma unroll
    for (int r = 0; r < 4; ++r) {
        int i = (l >> 4) * 4 + r;
        int j = l & 15;
        pr[i * 32 + j]             = c00[r];
        pr[i * 32 + 16 + j]        = c01[r];
        pr[(16 + i) * 32 + 16 + j] = c11[r];
    }
}

// ---------------------------------------------------------------------------
// Pass D: parallel reduce of part[2048][1024]; triangle map; scale 2^-60.
// ---------------------------------------------------------------------------
__global__ __launch_bounds__(256) void k_reduce(
    const float* __restrict__ part, float* __restrict__ out)
{
    __shared__ float red[16][17];
    const int t = threadIdx.x;
    const int sl    = t & 15;
    const int chunk = t >> 4;
    const int slot  = blockIdx.x * 16 + sl;
    float v = 0.0f;
    const int r0 = chunk * 128;
    for (int i = 0; i < 128; ++i)
        v += part[((size_t)(r0 + i) << 10) + slot];
    red[chunk][sl] = v;
    __syncthreads();
    if (t < 16) {
        float s = 0.0f;
        #pragma unroll
        for (int cch = 0; cch < 16; ++cch) s += red[cch][t];
        int sq = blockIdx.x * 16 + t;
        int i = sq >> 5, j = sq & 31;
        if (j >= i) {
            int q = 32 * i - (i * (i - 1)) / 2 + (j - i);
            if (q < 527) out[q] = s * 8.6736173798840355e-19f;   // 2^-60
        }
    }
}

// ---------------------------------------------------------------------------
extern "C" void kernel_launch(void* const* d_in, const int* in_sizes, int n_in,
                              void* d_out, int out_size, void* d_ws, size_t ws_size,
                              hipStream_t stream) {
    (void)in_sizes; (void)n_in; (void)out_size;
    const float*  xhat = (const float*)d_in[0];
    const float*  pre  = (const float*)d_in[1];
    const float*  pim  = (const float*)d_in[2];
    float* out = (float*)d_out;

    char* ws = (char*)d_ws;
    _Float16*     modb = (_Float16*)ws;                              // 64 MB
    float*        part = (float*)(ws + NWV * NPOINTS * 2ULL);        // 8 MB
    size_t        Toff = NWV * NPOINTS * 2ULL + 2048ULL * 1024ULL * 4ULL;
    unsigned int* T    = (unsigned int*)(ws + Toff);                 // WB*4 MB

    int WB = 1;
    const int cands[4] = {8, 4, 2, 1};
    for (int c = 0; c < 4; ++c)
        if (Toff + (size_t)cands[c] * NPOINTS * 4ULL <= ws_size) { WB = cands[c]; break; }

    for (int wb = 0; wb < NWV; wb += WB) {
        hipLaunchKernelGGL(k_rowfft, dim3(256, WB), dim3(256), 0, stream,
                           xhat, pre, pim, T, wb);
        hipLaunchKernelGGL(k_colfft, dim3(256, WB), dim3(256), 0, stream,
                           (const unsigned int*)T, modb, wb);
    }
    hipLaunchKernelGGL(k_gram, dim3(512), dim3(256), 0, stream,
                       (const _Float16*)modb, part);
    hipLaunchKernelGGL(k_reduce, dim3(64), dim3(256), 0, stream,
                       (const float*)part, out);
}

// Round 9
// 237.705 us; speedup vs baseline: 1.3403x; 1.1600x over previous
//
#include <hip/hip_runtime.h>

// NW=32 wavelets, N=M=1024.
#define NPOINTS 1048576ULL
#define NWV 32
#define ZSTR 40   // h16 stride of [k1][n2] Z planes (16B-aligned rows)
#define PSTR 34   // u32 stride of stage plane [n2][n1] (2-way-free banks)

typedef _Float16 h8 __attribute__((ext_vector_type(8)));
typedef _Float16 h2 __attribute__((ext_vector_type(2)));
typedef short    s8v __attribute__((ext_vector_type(8)));
typedef float    f32x4 __attribute__((ext_vector_type(4)));

// Scaling plan (rounds 3-8): no 1/(N*M) in the FFTs; conv' = 2^20*conv.
// mod' = sqrt(|conv'|^2 + 1e-8*2^40); final scale 2^-60 in k_reduce.

__device__ __forceinline__ f32x4 MF(h8 a, h8 b, f32x4 c) {
    return __builtin_amdgcn_mfma_f32_16x16x32_f16(a, b, c, 0, 0, 0);
}
__device__ __forceinline__ h8 hneg(h8 x) {
    s8v s = *(s8v*)&x;
    s = s ^ (short)0x8000;
    return *(h8*)&s;
}
// sin/cos of (2*pi*rev): hardware trans ops take REVOLUTIONS (cdna4_isa §3).
__device__ __forceinline__ float fsin_rev(float rev) {
    float r; asm("v_sin_f32 %0, %1" : "=v"(r) : "v"(rev)); return r;
}
__device__ __forceinline__ float fcos_rev(float rev) {
    float r; asm("v_cos_f32 %0, %1" : "=v"(r) : "v"(rev)); return r;
}

// Per-block tables: TW[a*32+b] = W1024^(a*b) (f32), F[a][b] = W32^(a*b) (f16).
// Args are exact dyadic rationals < 1 -> v_sin/v_cos accurate, cheap.
__device__ __forceinline__ void build_tables(int t, float2* TW, _Float16* Fr, _Float16* Fi) {
    for (int i = t; i < 1024; i += 256) {
        int a = i >> 5, b = i & 31;
        float rev1 = (float)(a * b) * (1.0f / 1024.0f);
        TW[i] = make_float2(fcos_rev(rev1), fsin_rev(rev1));
        float rev2 = (float)((a * b) & 31) * (1.0f / 32.0f);
        Fr[a * ZSTR + b] = (_Float16)fcos_rev(rev2);
        Fi[a * ZSTR + b] = (_Float16)fsin_rev(rev2);
    }
}

// Unpack staged u32 (h2{re,im}) plane into MFMA A-fragments.
// A[row=n2][k=n1]: lane (g,c16) takes n2 = c16 (+16), n1 = 8g..8g+7.
__device__ __forceinline__ void load_frags(const unsigned int* __restrict__ pl,
    int g, int c16, h8& ar0, h8& ai0, h8& ar1, h8& ai1)
{
    #pragma unroll
    for (int j = 0; j < 8; ++j) {
        unsigned int v0 = pl[PSTR * c16 + 8 * g + j];
        unsigned int v1 = pl[PSTR * (16 + c16) + 8 * g + j];
        h2 p0 = *(h2*)&v0, p1 = *(h2*)&v1;
        ar0[j] = p0.x; ai0[j] = p0.y;
        ar1[j] = p1.x; ai1[j] = p1.y;
    }
}

struct EOut { f32x4 r00, r01, r10, r11, i00, i01, i10, i11; };

// 1024-pt inverse FFT per wave, four-step 32x32 (validated rounds 7-8):
//  step1 D = X^T*F, twiddle by W1024^(n2*k1) staged f16 to wave-private Z,
//  step3 E = Z*F -> E[k1][k2], natural output order k = k1 + 32*k2.
__device__ __forceinline__ EOut fft_core(
    h8 ar0, h8 ai0, h8 ar1, h8 ai1,
    h8 fr0, h8 fr1, h8 fi0, h8 fi1, h8 mfi0, h8 mfi1,
    const float2* __restrict__ TW,
    _Float16* __restrict__ Zr, _Float16* __restrict__ Zi,
    int g, int c16)
{
    const f32x4 z = {0.f, 0.f, 0.f, 0.f};
    f32x4 dr00=z, dr01=z, dr10=z, dr11=z, di00=z, di01=z, di10=z, di11=z;
    dr00 = MF(ar0, fr0, dr00); dr00 = MF(ai0, mfi0, dr00);
    di00 = MF(ar0, fi0, di00); di00 = MF(ai0, fr0,  di00);
    dr01 = MF(ar0, fr1, dr01); dr01 = MF(ai0, mfi1, dr01);
    di01 = MF(ar0, fi1, di01); di01 = MF(ai0, fr1,  di01);
    dr10 = MF(ar1, fr0, dr10); dr10 = MF(ai1, mfi0, dr10);
    di10 = MF(ar1, fi0, di10); di10 = MF(ai1, fr0,  di10);
    dr11 = MF(ar1, fr1, dr11); dr11 = MF(ai1, mfi1, dr11);
    di11 = MF(ar1, fi1, di11); di11 = MF(ai1, fr1,  di11);

#define TWZ(DR, DI, QI, QJ)                                                    \
    {                                                                          \
        const int k1 = 16 * (QJ) + c16;                                        \
        _Pragma("unroll")                                                      \
        for (int rp = 0; rp < 2; ++rp) {                                       \
            const int n2 = 16 * (QI) + 4 * g + 2 * rp;                         \
            float2 tA = TW[n2 * 32 + k1];                                      \
            float2 tB = TW[(n2 + 1) * 32 + k1];                                \
            float yr0 = DR[2*rp],   yi0 = DI[2*rp];                            \
            float yr1 = DR[2*rp+1], yi1 = DI[2*rp+1];                          \
            h2 zr2 = { (_Float16)(yr0*tA.x - yi0*tA.y),                        \
                       (_Float16)(yr1*tB.x - yi1*tB.y) };                      \
            h2 zi2 = { (_Float16)(yi0*tA.x + yr0*tA.y),                        \
                       (_Float16)(yi1*tB.x + yr1*tB.y) };                      \
            *(h2*)&Zr[k1 * ZSTR + n2] = zr2;                                   \
            *(h2*)&Zi[k1 * ZSTR + n2] = zi2;                                   \
        }                                                                      \
    }
    TWZ(dr00, di00, 0, 0) TWZ(dr01, di01, 0, 1)
    TWZ(dr10, di10, 1, 0) TWZ(dr11, di11, 1, 1)
#undef TWZ

    h8 a3r0 = *(h8*)&Zr[c16 * ZSTR + 8 * g];
    h8 a3i0 = *(h8*)&Zi[c16 * ZSTR + 8 * g];
    h8 a3r1 = *(h8*)&Zr[(16 + c16) * ZSTR + 8 * g];
    h8 a3i1 = *(h8*)&Zi[(16 + c16) * ZSTR + 8 * g];

    EOut e;
    e.r00 = MF(a3r0, fr0, z); e.r00 = MF(a3i0, mfi0, e.r00);
    e.i00 = MF(a3r0, fi0, z); e.i00 = MF(a3i0, fr0,  e.i00);
    e.r01 = MF(a3r0, fr1, z); e.r01 = MF(a3i0, mfi1, e.r01);
    e.i01 = MF(a3r0, fi1, z); e.i01 = MF(a3i0, fr1,  e.i01);
    e.r10 = MF(a3r1, fr0, z); e.r10 = MF(a3i1, mfi0, e.r10);
    e.i10 = MF(a3r1, fi0, z); e.i10 = MF(a3i1, fr0,  e.i10);
    e.r11 = MF(a3r1, fr1, z); e.r11 = MF(a3i1, mfi1, e.r11);
    e.i11 = MF(a3r1, fi1, z); e.i11 = MF(a3i1, fr1,  e.i11);
    return e;
}

// ---------------------------------------------------------------------------
// Pass A: 4 waves/block = 4 rows of one wavelet. Vectorized dwordx4 loads in
// NATURAL order, pointwise complex multiply, h2-pack staged to per-wave LDS
// plane, fragment unpack, MFMA FFT, block transpose, T[k][n0..3] 16B stores.
// ---------------------------------------------------------------------------
__global__ __launch_bounds__(256, 4) void k_rowfft(
    const float* __restrict__ xhat, const float* __restrict__ pre,
    const float* __restrict__ pim, unsigned int* __restrict__ T, int wbase)
{
    __shared__ float2   TW[1024];
    __shared__ _Float16 Fr[1280], Fi[1280];
    __shared__ unsigned int WSP[4][1312];   // per-wave stage/Z union; Ttile union
    const int t = threadIdx.x, wv = t >> 6, l = t & 63, g = l >> 4, c16 = l & 15;
    const int n = blockIdx.x * 4 + wv;
    const int wl = blockIdx.y, w = wbase + wl;

    build_tables(t, TW, Fr, Fi);
    __syncthreads();

    h8 fr0 = *(h8*)&Fr[c16 * ZSTR + 8 * g];
    h8 fr1 = *(h8*)&Fr[(16 + c16) * ZSTR + 8 * g];
    h8 fi0 = *(h8*)&Fi[c16 * ZSTR + 8 * g];
    h8 fi1 = *(h8*)&Fi[(16 + c16) * ZSTR + 8 * g];
    h8 mfi0 = hneg(fi0), mfi1 = hneg(fi1);

    // Stage: m = 256c + 4l + i  ->  n1 = 8c + (l>>3), n2 = 4*(l&7) + i.
    unsigned int* pl = &WSP[wv][0];
    const float4* pr4 = (const float4*)(pre + (size_t)w * NPOINTS + (size_t)n * 1024);
    const float4* pi4 = (const float4*)(pim + (size_t)w * NPOINTS + (size_t)n * 1024);
    const float4* xh4 = (const float4*)(xhat + (size_t)n * 2048);  // 2 complex per float4
    const int n2b = 4 * (l & 7), n1b = l >> 3;
    #pragma unroll
    for (int c = 0; c < 4; ++c) {
        float4 a  = pr4[64 * c + l];
        float4 b  = pi4[64 * c + l];
        float4 x0 = xh4[128 * c + 2 * l];
        float4 x1 = xh4[128 * c + 2 * l + 1];
        float xr[4] = {x0.x, x0.z, x1.x, x1.z};
        float xi[4] = {x0.y, x0.w, x1.y, x1.w};
        float pa[4] = {a.x, a.y, a.z, a.w};
        float pb[4] = {b.x, b.y, b.z, b.w};
        const int n1 = 8 * c + n1b;
        #pragma unroll
        for (int i = 0; i < 4; ++i) {
            float re = xr[i] * pa[i] - xi[i] * pb[i];
            float im = xi[i] * pa[i] + xr[i] * pb[i];
            h2 p = {(_Float16)re, (_Float16)im};
            pl[PSTR * (n2b + i) + n1] = *(unsigned int*)&p;
        }
    }
    h8 ar0, ai0, ar1, ai1;
    load_frags(pl, g, c16, ar0, ai0, ar1, ai1);   // intra-wave: no barrier

    EOut e = fft_core(ar0, ai0, ar1, ai1, fr0, fr1, fi0, fi1, mfi0, mfi1,
                      TW, (_Float16*)&WSP[wv][0], (_Float16*)&WSP[wv][0] + 1280,
                      g, c16);

    __syncthreads();                 // all waves done with private planes
    unsigned int* Ttile = &WSP[0][0];       // [k2]*132 + [k1]*4 + wv
#define EMIT(ER, EI, QI, QJ)                                                   \
    _Pragma("unroll")                                                          \
    for (int r = 0; r < 4; ++r) {                                              \
        int k1 = 16 * (QI) + 4 * g + r, k2 = 16 * (QJ) + c16;                  \
        h2 p = { (_Float16)ER[r], (_Float16)EI[r] };                           \
        Ttile[k2 * 132 + k1 * 4 + wv] = *(unsigned int*)&p;                    \
    }
    EMIT(e.r00, e.i00, 0, 0) EMIT(e.r01, e.i01, 0, 1)
    EMIT(e.r10, e.i10, 1, 0) EMIT(e.r11, e.i11, 1, 1)
#undef EMIT
    __syncthreads();

    unsigned int* Tw = T + (size_t)wl * NPOINTS;
    const int n0 = blockIdx.x * 4;
    #pragma unroll
    for (int jj = 0; jj < 4; ++jj) {
        int k = t + 256 * jj;
        uint4 v = *(uint4*)&Ttile[(k >> 5) * 132 + (k & 31) * 4];
        *(uint4*)&Tw[(size_t)k * 1024 + n0] = v;
    }
}

// ---------------------------------------------------------------------------
// Pass B: 4 waves/block = 4 columns. Vectorized uint4 natural-order loads,
// LDS re-stage, fragment unpack, MFMA FFT, modulus packed h2 straight from
// registers (uint2 stores; consistent spatial permutation). Barrier-free
// after table build.
// ---------------------------------------------------------------------------
__global__ __launch_bounds__(256, 4) void k_colfft(
    const unsigned int* __restrict__ T, _Float16* __restrict__ modb, int wbase)
{
    __shared__ float2   TW[1024];
    __shared__ _Float16 Fr[1280], Fi[1280];
    __shared__ unsigned int WSP[4][1312];
    const int t = threadIdx.x, wv = t >> 6, l = t & 63, g = l >> 4, c16 = l & 15;
    const int k = blockIdx.x * 4 + wv;
    const int wl = blockIdx.y, w = wbase + wl;

    build_tables(t, TW, Fr, Fi);
    __syncthreads();

    h8 fr0 = *(h8*)&Fr[c16 * ZSTR + 8 * g];
    h8 fr1 = *(h8*)&Fr[(16 + c16) * ZSTR + 8 * g];
    h8 fi0 = *(h8*)&Fi[c16 * ZSTR + 8 * g];
    h8 fi1 = *(h8*)&Fi[(16 + c16) * ZSTR + 8 * g];
    h8 mfi0 = hneg(fi0), mfi1 = hneg(fi1);

    unsigned int* pl = &WSP[wv][0];
    const uint4* Tc4 = (const uint4*)(T + (size_t)wl * NPOINTS + (size_t)k * 1024);
    const int n2b = 4 * (l & 7), n1b = l >> 3;
    #pragma unroll
    for (int c = 0; c < 4; ++c) {
        uint4 v = Tc4[64 * c + l];
        const int n1 = 8 * c + n1b;
        pl[PSTR * (n2b + 0) + n1] = v.x;
        pl[PSTR * (n2b + 1) + n1] = v.y;
        pl[PSTR * (n2b + 2) + n1] = v.z;
        pl[PSTR * (n2b + 3) + n1] = v.w;
    }
    h8 ar0, ai0, ar1, ai1;
    load_frags(pl, g, c16, ar0, ai0, ar1, ai1);

    EOut e = fft_core(ar0, ai0, ar1, ai1, fr0, fr1, fi0, fi1, mfi0, mfi1,
                      TW, (_Float16*)&WSP[wv][0], (_Float16*)&WSP[wv][0] + 1280,
                      g, c16);

    // mod straight from registers: u32 idx = 256*QJ + 16*c16 + 8*QI + 2*g + rp.
    unsigned int* mo = (unsigned int*)(modb + (size_t)w * NPOINTS + (size_t)k * 1024);
    const float epsp = 1.09951162778e4f;   // 1e-8 * 2^40
#define EMITM(ER, EI, QI, QJ)                                                  \
    {                                                                          \
        float m0 = sqrtf(ER[0]*ER[0] + EI[0]*EI[0] + epsp);                    \
        float m1 = sqrtf(ER[1]*ER[1] + EI[1]*EI[1] + epsp);                    \
        float m2 = sqrtf(ER[2]*ER[2] + EI[2]*EI[2] + epsp);                    \
        float m3 = sqrtf(ER[3]*ER[3] + EI[3]*EI[3] + epsp);                    \
        h2 ha = {(_Float16)m0, (_Float16)m1};                                  \
        h2 hb = {(_Float16)m2, (_Float16)m3};                                  \
        uint2 uv = { *(unsigned int*)&ha, *(unsigned int*)&hb };               \
        *(uint2*)&mo[256 * (QJ) + 16 * c16 + 8 * (QI) + 2 * g] = uv;           \
    }
    EMITM(e.r00, e.i00, 0, 0) EMITM(e.r01, e.i01, 0, 1)
    EMITM(e.r10, e.i10, 1, 0) EMITM(e.r11, e.i11, 1, 1)
#undef EMITM
}

// ---------------------------------------------------------------------------
// Pass C: Gram partials via MFMA (validated). 2048 partial rows.
// ---------------------------------------------------------------------------
__global__ __launch_bounds__(256) void k_gram(
    const _Float16* __restrict__ modb, float* __restrict__ part)
{
    __shared__ _Float16 tile[32][520];
    const int t = threadIdx.x;
    const int l = t & 63, wv = t >> 6;
    f32x4 c00 = {0.f,0.f,0.f,0.f}, c01 = {0.f,0.f,0.f,0.f}, c11 = {0.f,0.f,0.f,0.f};
    const size_t pbase = (size_t)blockIdx.x * 2048;

    for (int tt = 0; tt < 4; ++tt) {
        __syncthreads();
        size_t p0 = pbase + (size_t)tt * 512;
        #pragma unroll
        for (int i = 0; i < 8; ++i) {
            int w = i * 4 + wv;
            *(h8*)&tile[w][(size_t)(l * 8)] =
                *(const h8*)&modb[((size_t)w << 20) + p0 + (size_t)(l * 8)];
        }
        __syncthreads();
        #pragma unroll
        for (int s = 0; s < 4; ++s) {
            int k0 = (s * 4 + wv) * 32 + ((l >> 4) * 8);
            h8 a0 = *(const h8*)&tile[l & 15][k0];
            h8 a1 = *(const h8*)&tile[16 + (l & 15)][k0];
            c00 = __builtin_amdgcn_mfma_f32_16x16x32_f16(a0, a0, c00, 0, 0, 0);
            c01 = __builtin_amdgcn_mfma_f32_16x16x32_f16(a0, a1, c01, 0, 0, 0);
            c11 = __builtin_amdgcn_mfma_f32_16x16x32_f16(a1, a1, c11, 0, 0, 0);
        }
    }
    const int row = (blockIdx.x << 2) | wv;
    float* pr = part + ((size_t)row << 10);
    #pragma unroll
    for (int r = 0; r < 4; ++r) {
        int i = (l >> 4) * 4 + r;
        int j = l & 15;
        pr[i * 32 + j]             = c00[r];
        pr[i * 32 + 16 + j]        = c01[r];
        pr[(16 + i) * 32 + 16 + j] = c11[r];
    }
}

// ---------------------------------------------------------------------------
// Pass D: parallel reduce of part[2048][1024]; triangle map; scale 2^-60.
// ---------------------------------------------------------------------------
__global__ __launch_bounds__(256) void k_reduce(
    const float* __restrict__ part, float* __restrict__ out)
{
    __shared__ float red[16][17];
    const int t = threadIdx.x;
    const int sl    = t & 15;
    const int chunk = t >> 4;
    const int slot  = blockIdx.x * 16 + sl;
    float v = 0.0f;
    const int r0 = chunk * 128;
    for (int i = 0; i < 128; ++i)
        v += part[((size_t)(r0 + i) << 10) + slot];
    red[chunk][sl] = v;
    __syncthreads();
    if (t < 16) {
        float s = 0.0f;
        #pragma unroll
        for (int cch = 0; cch < 16; ++cch) s += red[cch][t];
        int sq = blockIdx.x * 16 + t;
        int i = sq >> 5, j = sq & 31;
        if (j >= i) {
            int q = 32 * i - (i * (i - 1)) / 2 + (j - i);
            if (q < 527) out[q] = s * 8.6736173798840355e-19f;   // 2^-60
        }
    }
}

// ---------------------------------------------------------------------------
extern "C" void kernel_launch(void* const* d_in, const int* in_sizes, int n_in,
                              void* d_out, int out_size, void* d_ws, size_t ws_size,
                              hipStream_t stream) {
    (void)in_sizes; (void)n_in; (void)out_size;
    const float*  xhat = (const float*)d_in[0];
    const float*  pre  = (const float*)d_in[1];
    const float*  pim  = (const float*)d_in[2];
    float* out = (float*)d_out;

    char* ws = (char*)d_ws;
    _Float16*     modb = (_Float16*)ws;                              // 64 MB
    float*        part = (float*)(ws + NWV * NPOINTS * 2ULL);        // 8 MB
    size_t        Toff = NWV * NPOINTS * 2ULL + 2048ULL * 1024ULL * 4ULL;
    unsigned int* T    = (unsigned int*)(ws + Toff);                 // WB*4 MB

    // WB=32 preferred: 4 dispatches total, no inter-batch serialization.
    int WB = 1;
    const int cands[6] = {32, 16, 8, 4, 2, 1};
    for (int c = 0; c < 6; ++c)
        if (Toff + (size_t)cands[c] * NPOINTS * 4ULL <= ws_size) { WB = cands[c]; break; }

    for (int wb = 0; wb < NWV; wb += WB) {
        hipLaunchKernelGGL(k_rowfft, dim3(256, WB), dim3(256), 0, stream,
                           xhat, pre, pim, T, wb);
        hipLaunchKernelGGL(k_colfft, dim3(256, WB), dim3(256), 0, stream,
                           (const unsigned int*)T, modb, wb);
    }
    hipLaunchKernelGGL(k_gram, dim3(512), dim3(256), 0, stream,
                       (const _Float16*)modb, part);
    hipLaunchKernelGGL(k_reduce, dim3(64), dim3(256), 0, stream,
                       (const float*)part, out);
}

// Round 10
// 164.747 us; speedup vs baseline: 1.9338x; 1.4429x over previous
//
#include <hip/hip_runtime.h>

// NW=32 wavelets, N=M=1024.
#define NPOINTS 1048576ULL
#define NWV 32
#define ZSTR 40   // h16 stride of [k1][n2] Z planes (16B-aligned rows)
#define PSTR 33   // u32 stride of stage plane [n2][n1] (odd -> <=2-way banks)

typedef _Float16 h8 __attribute__((ext_vector_type(8)));
typedef _Float16 h2 __attribute__((ext_vector_type(2)));
typedef short    s8v __attribute__((ext_vector_type(8)));
typedef float    f32x4 __attribute__((ext_vector_type(4)));

// Scaling plan (rounds 3-9): no 1/(N*M) in the FFTs; conv' = 2^20*conv.
// mod' = sqrt(|conv'|^2 + 1e-8*2^40); final scale 2^-60 in k_reduce.

__device__ __forceinline__ f32x4 MF(h8 a, h8 b, f32x4 c) {
    return __builtin_amdgcn_mfma_f32_16x16x32_f16(a, b, c, 0, 0, 0);
}
__device__ __forceinline__ h8 hneg(h8 x) {
    s8v s = *(s8v*)&x;
    s = s ^ (short)0x8000;
    return *(h8*)&s;
}
// sin/cos of (2*pi*rev): hardware trans ops take REVOLUTIONS (cdna4_isa §3).
__device__ __forceinline__ float fsin_rev(float rev) {
    float r; asm("v_sin_f32 %0, %1" : "=v"(r) : "v"(rev)); return r;
}
__device__ __forceinline__ float fcos_rev(float rev) {
    float r; asm("v_cos_f32 %0, %1" : "=v"(r) : "v"(rev)); return r;
}

// Per-lane F32 fragments: F[a][b] = W32^(a*b); lane (g,c16) holds rows
// {c16, 16+c16}, k = 8g..8g+7. Exact dyadic args -> identical to r9's table.
__device__ __forceinline__ void build_ffrags(int g, int c16,
    h8& fr0, h8& fi0, h8& fr1, h8& fi1)
{
    #pragma unroll
    for (int j = 0; j < 8; ++j) {
        int b = 8 * g + j;
        float r0 = (float)((c16 * b) & 31) * (1.0f / 32.0f);
        float r1 = (float)(((16 + c16) * b) & 31) * (1.0f / 32.0f);
        fr0[j] = (_Float16)fcos_rev(r0); fi0[j] = (_Float16)fsin_rev(r0);
        fr1[j] = (_Float16)fcos_rev(r1); fi1[j] = (_Float16)fsin_rev(r1);
    }
}

// Unpack staged u32 (h2{re,im}) plane into MFMA A-fragments.
__device__ __forceinline__ void load_frags(const unsigned int* __restrict__ pl,
    int g, int c16, h8& ar0, h8& ai0, h8& ar1, h8& ai1)
{
    #pragma unroll
    for (int j = 0; j < 8; ++j) {
        unsigned int v0 = pl[PSTR * c16 + 8 * g + j];
        unsigned int v1 = pl[PSTR * (16 + c16) + 8 * g + j];
        h2 p0 = *(h2*)&v0, p1 = *(h2*)&v1;
        ar0[j] = p0.x; ai0[j] = p0.y;
        ar1[j] = p1.x; ai1[j] = p1.y;
    }
}

struct EOut { f32x4 r00, r01, r10, r11, i00, i01, i10, i11; };

// 1024-pt inverse FFT per wave, four-step 32x32 (validated rounds 7-9):
// TW twiddles computed inline via v_sin/v_cos (exact integer*2^-10 args).
__device__ __forceinline__ EOut fft_core(
    h8 ar0, h8 ai0, h8 ar1, h8 ai1,
    h8 fr0, h8 fr1, h8 fi0, h8 fi1, h8 mfi0, h8 mfi1,
    _Float16* __restrict__ Zr, _Float16* __restrict__ Zi,
    int g, int c16)
{
    const f32x4 z = {0.f, 0.f, 0.f, 0.f};
    f32x4 dr00=z, dr01=z, dr10=z, dr11=z, di00=z, di01=z, di10=z, di11=z;
    dr00 = MF(ar0, fr0, dr00); dr00 = MF(ai0, mfi0, dr00);
    di00 = MF(ar0, fi0, di00); di00 = MF(ai0, fr0,  di00);
    dr01 = MF(ar0, fr1, dr01); dr01 = MF(ai0, mfi1, dr01);
    di01 = MF(ar0, fi1, di01); di01 = MF(ai0, fr1,  di01);
    dr10 = MF(ar1, fr0, dr10); dr10 = MF(ai1, mfi0, dr10);
    di10 = MF(ar1, fi0, di10); di10 = MF(ai1, fr0,  di10);
    dr11 = MF(ar1, fr1, dr11); dr11 = MF(ai1, mfi1, dr11);
    di11 = MF(ar1, fi1, di11); di11 = MF(ai1, fr1,  di11);

#define TWZ(DR, DI, QI, QJ)                                                    \
    {                                                                          \
        const int k1 = 16 * (QJ) + c16;                                        \
        _Pragma("unroll")                                                      \
        for (int rp = 0; rp < 2; ++rp) {                                       \
            const int n2 = 16 * (QI) + 4 * g + 2 * rp;                         \
            float rA = (float)(n2 * k1) * (1.0f / 1024.0f);                    \
            float rB = (float)((n2 + 1) * k1) * (1.0f / 1024.0f);              \
            float2 tA = make_float2(fcos_rev(rA), fsin_rev(rA));               \
            float2 tB = make_float2(fcos_rev(rB), fsin_rev(rB));               \
            float yr0 = DR[2*rp],   yi0 = DI[2*rp];                            \
            float yr1 = DR[2*rp+1], yi1 = DI[2*rp+1];                          \
            h2 zr2 = { (_Float16)(yr0*tA.x - yi0*tA.y),                        \
                       (_Float16)(yr1*tB.x - yi1*tB.y) };                      \
            h2 zi2 = { (_Float16)(yi0*tA.x + yr0*tA.y),                        \
                       (_Float16)(yi1*tB.x + yr1*tB.y) };                      \
            *(h2*)&Zr[k1 * ZSTR + n2] = zr2;                                   \
            *(h2*)&Zi[k1 * ZSTR + n2] = zi2;                                   \
        }                                                                      \
    }
    TWZ(dr00, di00, 0, 0) TWZ(dr01, di01, 0, 1)
    TWZ(dr10, di10, 1, 0) TWZ(dr11, di11, 1, 1)
#undef TWZ

    h8 a3r0 = *(h8*)&Zr[c16 * ZSTR + 8 * g];
    h8 a3i0 = *(h8*)&Zi[c16 * ZSTR + 8 * g];
    h8 a3r1 = *(h8*)&Zr[(16 + c16) * ZSTR + 8 * g];
    h8 a3i1 = *(h8*)&Zi[(16 + c16) * ZSTR + 8 * g];

    EOut e;
    e.r00 = MF(a3r0, fr0, z); e.r00 = MF(a3i0, mfi0, e.r00);
    e.i00 = MF(a3r0, fi0, z); e.i00 = MF(a3i0, fr0,  e.i00);
    e.r01 = MF(a3r0, fr1, z); e.r01 = MF(a3i0, mfi1, e.r01);
    e.i01 = MF(a3r0, fi1, z); e.i01 = MF(a3i0, fr1,  e.i01);
    e.r10 = MF(a3r1, fr0, z); e.r10 = MF(a3i1, mfi0, e.r10);
    e.i10 = MF(a3r1, fi0, z); e.i10 = MF(a3i1, fr0,  e.i10);
    e.r11 = MF(a3r1, fr1, z); e.r11 = MF(a3i1, mfi1, e.r11);
    e.i11 = MF(a3r1, fi1, z); e.i11 = MF(a3i1, fr1,  e.i11);
    return e;
}

// ---------------------------------------------------------------------------
// Pass A: 4 waves/block = 4 rows of one wavelet. Vectorized natural-order
// loads, pointwise cmul, LDS stage, MFMA FFT, block transpose, then
// PERFECTLY COALESCED stores to T[nb][k][4n] (byte addr nb*16K + k*16).
// LDS = 21 KB (no tables) -> up to 7 blocks/CU.
// ---------------------------------------------------------------------------
__global__ __launch_bounds__(256, 6) void k_rowfft(
    const float* __restrict__ xhat, const float* __restrict__ pre,
    const float* __restrict__ pim, unsigned int* __restrict__ T, int wbase)
{
    __shared__ unsigned int WSP[4][1312];   // per-wave stage/Z union; Ttile union
    const int t = threadIdx.x, wv = t >> 6, l = t & 63, g = l >> 4, c16 = l & 15;
    const int n = blockIdx.x * 4 + wv;
    const int wl = blockIdx.y, w = wbase + wl;

    h8 fr0, fi0, fr1, fi1;
    build_ffrags(g, c16, fr0, fi0, fr1, fi1);
    h8 mfi0 = hneg(fi0), mfi1 = hneg(fi1);

    // Stage: m = 256c + 4l + i  ->  n1 = 8c + (l>>3), n2 = 4*(l&7) + i.
    unsigned int* pl = &WSP[wv][0];
    const float4* pr4 = (const float4*)(pre + (size_t)w * NPOINTS + (size_t)n * 1024);
    const float4* pi4 = (const float4*)(pim + (size_t)w * NPOINTS + (size_t)n * 1024);
    const float4* xh4 = (const float4*)(xhat + (size_t)n * 2048);  // 2 complex per float4
    const int n2b = 4 * (l & 7), n1b = l >> 3;
    #pragma unroll
    for (int c = 0; c < 4; ++c) {
        float4 a  = pr4[64 * c + l];
        float4 b  = pi4[64 * c + l];
        float4 x0 = xh4[128 * c + 2 * l];
        float4 x1 = xh4[128 * c + 2 * l + 1];
        float xr[4] = {x0.x, x0.z, x1.x, x1.z};
        float xi[4] = {x0.y, x0.w, x1.y, x1.w};
        float pa[4] = {a.x, a.y, a.z, a.w};
        float pb[4] = {b.x, b.y, b.z, b.w};
        const int n1 = 8 * c + n1b;
        #pragma unroll
        for (int i = 0; i < 4; ++i) {
            float re = xr[i] * pa[i] - xi[i] * pb[i];
            float im = xi[i] * pa[i] + xr[i] * pb[i];
            h2 p = {(_Float16)re, (_Float16)im};
            pl[PSTR * (n2b + i) + n1] = *(unsigned int*)&p;
        }
    }
    h8 ar0, ai0, ar1, ai1;
    load_frags(pl, g, c16, ar0, ai0, ar1, ai1);   // intra-wave: no barrier

    EOut e = fft_core(ar0, ai0, ar1, ai1, fr0, fr1, fi0, fi1, mfi0, mfi1,
                      (_Float16*)&WSP[wv][0], (_Float16*)&WSP[wv][0] + 1280,
                      g, c16);

    __syncthreads();                 // all waves done with private planes
    unsigned int* Ttile = &WSP[0][0];       // [k2]*132 + [k1]*4 + wv
#define EMIT(ER, EI, QI, QJ)                                                   \
    _Pragma("unroll")                                                          \
    for (int r = 0; r < 4; ++r) {                                              \
        int k1 = 16 * (QI) + 4 * g + r, k2 = 16 * (QJ) + c16;                  \
        h2 p = { (_Float16)ER[r], (_Float16)EI[r] };                           \
        Ttile[k2 * 132 + k1 * 4 + wv] = *(unsigned int*)&p;                    \
    }
    EMIT(e.r00, e.i00, 0, 0) EMIT(e.r01, e.i01, 0, 1)
    EMIT(e.r10, e.i10, 1, 0) EMIT(e.r11, e.i11, 1, 1)
#undef EMIT
    __syncthreads();

    // T[nb][k][j]: u32 idx = nb*4096 + k*4 + j. Consecutive t -> +16B.
    unsigned int* Tw = T + (size_t)wl * NPOINTS;
    const size_t nb = (size_t)blockIdx.x;
    #pragma unroll
    for (int jj = 0; jj < 4; ++jj) {
        int k = t + 256 * jj;
        uint4 v = *(uint4*)&Ttile[(k >> 5) * 132 + (k & 31) * 4];
        *(uint4*)&Tw[nb * 4096 + (size_t)k * 4] = v;
    }
}

// ---------------------------------------------------------------------------
// Pass B: 4 waves/block = 4 consecutive columns k0..k0+3. Thread t reads one
// full 64B line (4x uint4: nb=t, k=k0..k0+3), scatters to the 4 wave planes,
// ONE barrier, then per-wave MFMA FFT + modulus from registers (coalesced).
// ---------------------------------------------------------------------------
__global__ __launch_bounds__(256, 6) void k_colfft(
    const unsigned int* __restrict__ T, _Float16* __restrict__ modb, int wbase)
{
    __shared__ unsigned int WSP[4][1312];
    const int t = threadIdx.x, wv = t >> 6, l = t & 63, g = l >> 4, c16 = l & 15;
    const int k0 = blockIdx.x * 4, k = k0 + wv;
    const int wl = blockIdx.y, w = wbase + wl;

    h8 fr0, fi0, fr1, fi1;
    build_ffrags(g, c16, fr0, fi0, fr1, fi1);
    h8 mfi0 = hneg(fi0), mfi1 = hneg(fi1);

    // Cooperative read + cross-wave exchange: thread t = nb, n = 4t+j.
    const unsigned int* Tc = T + (size_t)wl * NPOINTS;
    const int en2 = 4 * (t & 7), en1 = t >> 3;
    #pragma unroll
    for (int c = 0; c < 4; ++c) {
        uint4 v = *(const uint4*)&Tc[(size_t)t * 4096 + (size_t)(k0 + c) * 4];
        unsigned int* plc = &WSP[c][0];
        plc[PSTR * (en2 + 0) + en1] = v.x;
        plc[PSTR * (en2 + 1) + en1] = v.y;
        plc[PSTR * (en2 + 2) + en1] = v.z;
        plc[PSTR * (en2 + 3) + en1] = v.w;
    }
    __syncthreads();

    h8 ar0, ai0, ar1, ai1;
    load_frags(&WSP[wv][0], g, c16, ar0, ai0, ar1, ai1);

    EOut e = fft_core(ar0, ai0, ar1, ai1, fr0, fr1, fi0, fi1, mfi0, mfi1,
                      (_Float16*)&WSP[wv][0], (_Float16*)&WSP[wv][0] + 1280,
                      g, c16);

    // mod straight from registers: u32 idx = 256*QJ + 16*c16 + 8*QI + 2*g + rp.
    unsigned int* mo = (unsigned int*)(modb + (size_t)w * NPOINTS + (size_t)k * 1024);
    const float epsp = 1.09951162778e4f;   // 1e-8 * 2^40
#define EMITM(ER, EI, QI, QJ)                                                  \
    {                                                                          \
        float m0 = sqrtf(ER[0]*ER[0] + EI[0]*EI[0] + epsp);                    \
        float m1 = sqrtf(ER[1]*ER[1] + EI[1]*EI[1] + epsp);                    \
        float m2 = sqrtf(ER[2]*ER[2] + EI[2]*EI[2] + epsp);                    \
        float m3 = sqrtf(ER[3]*ER[3] + EI[3]*EI[3] + epsp);                    \
        h2 ha = {(_Float16)m0, (_Float16)m1};                                  \
        h2 hb = {(_Float16)m2, (_Float16)m3};                                  \
        uint2 uv = { *(unsigned int*)&ha, *(unsigned int*)&hb };               \
        *(uint2*)&mo[256 * (QJ) + 16 * c16 + 8 * (QI) + 2 * g] = uv;           \
    }
    EMITM(e.r00, e.i00, 0, 0) EMITM(e.r01, e.i01, 0, 1)
    EMITM(e.r10, e.i10, 1, 0) EMITM(e.r11, e.i11, 1, 1)
#undef EMITM
}

// ---------------------------------------------------------------------------
// Pass C: Gram partials via MFMA (validated). 2048 partial rows.
// ---------------------------------------------------------------------------
__global__ __launch_bounds__(256) void k_gram(
    const _Float16* __restrict__ modb, float* __restrict__ part)
{
    __shared__ _Float16 tile[32][520];
    const int t = threadIdx.x;
    const int l = t & 63, wv = t >> 6;
    f32x4 c00 = {0.f,0.f,0.f,0.f}, c01 = {0.f,0.f,0.f,0.f}, c11 = {0.f,0.f,0.f,0.f};
    const size_t pbase = (size_t)blockIdx.x * 2048;

    for (int tt = 0; tt < 4; ++tt) {
        __syncthreads();
        size_t p0 = pbase + (size_t)tt * 512;
        #pragma unroll
        for (int i = 0; i < 8; ++i) {
            int w = i * 4 + wv;
            *(h8*)&tile[w][(size_t)(l * 8)] =
                *(const h8*)&modb[((size_t)w << 20) + p0 + (size_t)(l * 8)];
        }
        __syncthreads();
        #pragma unroll
        for (int s = 0; s < 4; ++s) {
            int k0 = (s * 4 + wv) * 32 + ((l >> 4) * 8);
            h8 a0 = *(const h8*)&tile[l & 15][k0];
            h8 a1 = *(const h8*)&tile[16 + (l & 15)][k0];
            c00 = __builtin_amdgcn_mfma_f32_16x16x32_f16(a0, a0, c00, 0, 0, 0);
            c01 = __builtin_amdgcn_mfma_f32_16x16x32_f16(a0, a1, c01, 0, 0, 0);
            c11 = __builtin_amdgcn_mfma_f32_16x16x32_f16(a1, a1, c11, 0, 0, 0);
        }
    }
    const int row = (blockIdx.x << 2) | wv;
    float* pr = part + ((size_t)row << 10);
    #pragma unroll
    for (int r = 0; r < 4; ++r) {
        int i = (l >> 4) * 4 + r;
        int j = l & 15;
        pr[i * 32 + j]             = c00[r];
        pr[i * 32 + 16 + j]        = c01[r];
        pr[(16 + i) * 32 + 16 + j] = c11[r];
    }
}

// ---------------------------------------------------------------------------
// Pass D: parallel reduce of part[2048][1024]; triangle map; scale 2^-60.
// ---------------------------------------------------------------------------
__global__ __launch_bounds__(256) void k_reduce(
    const float* __restrict__ part, float* __restrict__ out)
{
    __shared__ float red[16][17];
    const int t = threadIdx.x;
    const int sl    = t & 15;
    const int chunk = t >> 4;
    const int slot  = blockIdx.x * 16 + sl;
    float v = 0.0f;
    const int r0 = chunk * 128;
    for (int i = 0; i < 128; ++i)
        v += part[((size_t)(r0 + i) << 10) + slot];
    red[chunk][sl] = v;
    __syncthreads();
    if (t < 16) {
        float s = 0.0f;
        #pragma unroll
        for (int cch = 0; cch < 16; ++cch) s += red[cch][t];
        int sq = blockIdx.x * 16 + t;
        int i = sq >> 5, j = sq & 31;
        if (j >= i) {
            int q = 32 * i - (i * (i - 1)) / 2 + (j - i);
            if (q < 527) out[q] = s * 8.6736173798840355e-19f;   // 2^-60
        }
    }
}

// ---------------------------------------------------------------------------
extern "C" void kernel_launch(void* const* d_in, const int* in_sizes, int n_in,
                              void* d_out, int out_size, void* d_ws, size_t ws_size,
                              hipStream_t stream) {
    (void)in_sizes; (void)n_in; (void)out_size;
    const float*  xhat = (const float*)d_in[0];
    const float*  pre  = (const float*)d_in[1];
    const float*  pim  = (const float*)d_in[2];
    float* out = (float*)d_out;

    char* ws = (char*)d_ws;
    _Float16*     modb = (_Float16*)ws;                              // 64 MB
    float*        part = (float*)(ws + NWV * NPOINTS * 2ULL);        // 8 MB
    size_t        Toff = NWV * NPOINTS * 2ULL + 2048ULL * 1024ULL * 4ULL;
    unsigned int* T    = (unsigned int*)(ws + Toff);                 // WB*4 MB

    // WB=32 preferred: 4 dispatches total, no inter-batch serialization.
    int WB = 1;
    const int cands[6] = {32, 16, 8, 4, 2, 1};
    for (int c = 0; c < 6; ++c)
        if (Toff + (size_t)cands[c] * NPOINTS * 4ULL <= ws_size) { WB = cands[c]; break; }

    for (int wb = 0; wb < NWV; wb += WB) {
        hipLaunchKernelGGL(k_rowfft, dim3(256, WB), dim3(256), 0, stream,
                           xhat, pre, pim, T, wb);
        hipLaunchKernelGGL(k_colfft, dim3(256, WB), dim3(256), 0, stream,
                           (const unsigned int*)T, modb, wb);
    }
    hipLaunchKernelGGL(k_gram, dim3(512), dim3(256), 0, stream,
                       (const _Float16*)modb, part);
    hipLaunchKernelGGL(k_reduce, dim3(64), dim3(256), 0, stream,
                       (const float*)part, out);
}